// Round 11
// baseline (617.412 us; speedup 1.0000x reference)
//
#include <hip/hip_runtime.h>
#include <cstdint>
#include <cstddef>

// ---------------------------------------------------------------------------
// DeeperGCN forward on MI355X. Round 31: R30 (568.2us, best) + WIDE agg
// gather iterations. The layer is latency-bound (occ 26%, VALU 20%, HBM 5%);
// the serial chain is agg's inner loop: 8 j-steps/iter -> issue 16 rows,
// wait ~700cy L3, consume ~450cy VALU, repeat. Widening to 16 j-steps/iter
// (rv[2][8]) HALVES the latency windows (mean-degree chunk: 2->1, heavy: 5->3)
// with loads still guarded (no extra traffic -- R25's mistake) and no manual
// buffers (compiler schedules the 16 independent guarded loads together).
// +~16 VGPR, still far under the 256 cap at 8 waves/block.
// Everything else byte-identical to R30: xb deleted (enc reads x fp32 via
// ext_vector f32x2 nontemporal), scan+sort merged, 16-row tiles, 625 blocks,
// degree-sorted remap, 2 nodes/wave, max-free softmax, exp2-folded, MFMA
// GEMMs, h stream bf16, nt hints.
// N=10000 nodes, E=160000 edges, H=128, L=14 layers, G=64 graphs.
// ---------------------------------------------------------------------------

#define BT 512  // 8 waves

typedef __attribute__((ext_vector_type(8))) short bf16x8;
typedef __attribute__((ext_vector_type(4))) float f32x4;
typedef __attribute__((ext_vector_type(2))) float f32x2;

__device__ inline float bf2f(ushort u) {
    union { uint i; float f; } v;
    v.i = (uint)u << 16;
    return v.f;
}
__device__ inline ushort f2bf(float f) {
    union { float f; uint i; } v;
    v.f = f;
    return (ushort)((v.i + 0x7fffu + ((v.i >> 16) & 1u)) >> 16);
}
__device__ inline uint f2bf2(float a, float b) {
    return (uint)f2bf(a) | ((uint)f2bf(b) << 16);
}
__device__ inline float fast_exp2(float x) {
    return __builtin_amdgcn_exp2f(x);  // v_exp_f32: D = 2^S0
}

// ---------------- setup: deg histogram + graph boundaries ------------------
__global__ void setup_kernel(const int* __restrict__ dst, int* __restrict__ deg,
                             const int* __restrict__ batch, int* __restrict__ gstart,
                             int N, int E, int G) {
    int idx = blockIdx.x * blockDim.x + threadIdx.x;
    if (idx >= E) return;
    atomicAdd(&deg[dst[idx]], 1);
    if (idx < N) {
        int bb = batch[idx];
        if (idx == 0)
            for (int g = 0; g <= bb; g++) gstart[g] = 0;
        else {
            int pb = batch[idx - 1];
            for (int g = pb + 1; g <= bb; g++) gstart[g] = idx;
        }
        if (idx == N - 1)
            for (int g = bb + 1; g <= G; g++) gstart[g] = N;
    }
}

// single-workgroup: exclusive scan of deg -> offs/cursor, then counting sort
// (perm = node ids by DESCENDING degree). Merged to save one serial launch.
__global__ __launch_bounds__(1024) void scan_sort_kernel(const int* __restrict__ deg,
                                                         int* __restrict__ offs,
                                                         int* __restrict__ cursor,
                                                         int* __restrict__ perm, int N) {
    __shared__ int part[1024];
    __shared__ int hist[256];
    __shared__ int cur[256];
    int tid = threadIdx.x;
    int CH = (N + 1023) / 1024;
    int base = tid * CH;
    int s = 0;
    for (int i = 0; i < CH; i++) {
        int idx = base + i;
        if (idx < N) s += deg[idx];
    }
    part[tid] = s;
    __syncthreads();
    for (int off = 1; off < 1024; off <<= 1) {
        int v = (tid >= off) ? part[tid - off] : 0;
        __syncthreads();
        part[tid] += v;
        __syncthreads();
    }
    int run = (tid == 0) ? 0 : part[tid - 1];
    for (int i = 0; i < CH; i++) {
        int idx = base + i;
        if (idx < N) {
            offs[idx] = run;
            cursor[idx] = run;
            run += deg[idx];
        }
    }
    if (tid == 1023) offs[N] = part[1023];

    // ---- counting sort by degree (descending) ----
    if (tid < 256) hist[tid] = 0;
    __syncthreads();
    for (int n = tid; n < N; n += 1024) {
        int key = 255 - min(deg[n], 255);
        atomicAdd(&hist[key], 1);
    }
    __syncthreads();
    if (tid == 0) {
        int r = 0;
        for (int i = 0; i < 256; i++) {
            cur[i] = r;
            r += hist[i];
        }
    }
    __syncthreads();
    for (int n = tid; n < N; n += 1024) {
        int key = 255 - min(deg[n], 255);
        int pos = atomicAdd(&cur[key], 1);
        perm[pos] = n;
    }
}

__global__ void scatter_kernel(const int* __restrict__ src, const int* __restrict__ dst,
                               int* __restrict__ cursor, int* __restrict__ esrc, int E) {
    int e = blockIdx.x * blockDim.x + threadIdx.x;
    if (e < E) {
        int d = dst[e];
        int pos = atomicAdd(&cursor[d], 1);
        esrc[pos] = src[e];
    }
}

// ---------------- weight prep: fp32 [R][C] -> bf16 [C][R], all matrices ----
__global__ __launch_bounds__(256) void prep_kernel(const float* __restrict__ W1,
                                                   const float* __restrict__ W2,
                                                   const float* __restrict__ encW,
                                                   ushort* __restrict__ W1t,
                                                   ushort* __restrict__ W2t,
                                                   ushort* __restrict__ encWt, int L) {
    __shared__ float tile[32][33];
    int z = blockIdx.z;
    const float* in;
    ushort* out;
    int R, C;
    if (z < L) {
        in = W1 + (size_t)z * 32768; out = W1t + (size_t)z * 32768; R = 128; C = 256;
    } else if (z < 2 * L) {
        int i = z - L;
        in = W2 + (size_t)i * 32768; out = W2t + (size_t)i * 32768; R = 256; C = 128;
    } else {
        in = encW; out = encWt; R = 128; C = 128;
    }
    int r0 = blockIdx.y * 32, c0 = blockIdx.x * 32;
    if (r0 >= R || c0 >= C) return;
    int tx = threadIdx.x & 31, ty = threadIdx.x >> 5;
    for (int i = ty; i < 32; i += 8) tile[i][tx] = in[(size_t)(r0 + i) * C + c0 + tx];
    __syncthreads();
    for (int i = ty; i < 32; i += 8)
        out[(size_t)(c0 + i) * R + r0 + tx] = f2bf(tile[tx][i]);
}

// ---- aggregation: 2 (perm-adjacent, equal-degree) nodes/wave --------------
// WIDE iterations: 16 j-steps (32 guarded row-gathers/wave) per inner iter
// -> half the serial L3-latency windows of the 8-step version.
__device__ __forceinline__ void agg_stage(const ushort* __restrict__ rin,
                                          const int* __restrict__ offs,
                                          const int* __restrict__ esrc,
                                          const float* __restrict__ rnbuf,
                                          float tv2, float sv,
                                          int nd0, int nd1,
                                          int w, int l, uint (*AsU)[68]) {
    const uint2* rin2 = (const uint2*)rin;
    int half = l >> 5, li = l & 31;
    int eb[2], dg[2];
    eb[0] = offs[nd0]; dg[0] = offs[nd0 + 1] - eb[0];
    eb[1] = offs[nd1]; dg[1] = offs[nd1 + 1] - eb[1];

    // prefetch (independent of gather loop): own rows + rn for both nodes
    uint2 ru0 = rin2[(size_t)nd0 * 32 + li];
    uint2 ru1 = rin2[(size_t)nd1 * 32 + li];
    float rn0 = rnbuf[nd0], rn1 = rnbuf[nd1];

    float s[2][4] = {}, W[2][4] = {};
    int mxdeg = max(dg[0], dg[1]);

#pragma unroll 1
    for (int base = 0; base < mxdeg; base += 64) {
        int rem0 = min(dg[0] - base, 64);
        int rem1 = min(dg[1] - base, 64);
        int idx0 = (rem0 > 0 && l < rem0) ? esrc[eb[0] + base + l] : 0;
        int idx1 = (rem1 > 0 && l < rem1) ? esrc[eb[1] + base + l] : 0;
        int it = (max(rem0, rem1) + 15) >> 4;
#pragma unroll 1
        for (int i = 0; i < it; i++) {
            int j0 = i * 16 + half;
            uint2 rv[2][8];
            bool vl[2][8];
#pragma unroll
            for (int c = 0; c < 8; c++) {
                int j = j0 + 2 * c;
                vl[0][c] = j < rem0;
                vl[1][c] = j < rem1;
                int sn0 = __shfl(idx0, j, 64);
                int sn1 = __shfl(idx1, j, 64);
                if (vl[0][c]) rv[0][c] = rin2[(size_t)sn0 * 32 + li];
                if (vl[1][c]) rv[1][c] = rin2[(size_t)sn1 * 32 + li];
            }
#pragma unroll
            for (int k = 0; k < 2; k++)
#pragma unroll
                for (int c = 0; c < 8; c++) {
                    if (vl[k][c]) {
                        float f0 = bf2f((ushort)(rv[k][c].x & 0xffff));
                        float f1 = bf2f((ushort)(rv[k][c].x >> 16));
                        float f2 = bf2f((ushort)(rv[k][c].y & 0xffff));
                        float f3 = bf2f((ushort)(rv[k][c].y >> 16));
                        float g0 = fmaxf(f0, 0.f) + 1e-7f;
                        float g1 = fmaxf(f1, 0.f) + 1e-7f;
                        float g2 = fmaxf(f2, 0.f) + 1e-7f;
                        float g3 = fmaxf(f3, 0.f) + 1e-7f;
                        float p0 = fast_exp2(g0 * tv2);
                        float p1 = fast_exp2(g1 * tv2);
                        float p2 = fast_exp2(g2 * tv2);
                        float p3 = fast_exp2(g3 * tv2);
                        s[k][0] += p0; W[k][0] += g0 * p0;
                        s[k][1] += p1; W[k][1] += g1 * p1;
                        s[k][2] += p2; W[k][2] += g2 * p2;
                        s[k][3] += p3; W[k][3] += g3 * p3;
                    }
                }
        }
    }

    // merge halves (associative sums), then per-node epilogue
#pragma unroll
    for (int k = 0; k < 2; k++) {
#pragma unroll
        for (int f = 0; f < 4; f++) {
            s[k][f] += __shfl_xor(s[k][f], 32, 64);
            W[k][f] += __shfl_xor(W[k][f], 32, 64);
        }
        float agg[4], nsq = 0.f;
#pragma unroll
        for (int f = 0; f < 4; f++) {
            agg[f] = W[k][f] / (s[k][f] + 1e-16f);
            nsq += agg[f] * agg[f];
        }
#pragma unroll
        for (int off = 1; off < 32; off <<= 1) nsq += __shfl_xor(nsq, off, 64);
        float rnv = (k == 0) ? rn0 : rn1;
        uint2 ru = (k == 0) ? ru0 : ru1;
        float fac = rnv * sv / fmaxf(sqrtf(nsq), 1e-12f);
        if (half == 0) {
            uint2 o;
            o.x = f2bf2(bf2f((ushort)(ru.x & 0xffff)) + agg[0] * fac,
                        bf2f((ushort)(ru.x >> 16)) + agg[1] * fac);
            o.y = f2bf2(bf2f((ushort)(ru.y & 0xffff)) + agg[2] * fac,
                        bf2f((ushort)(ru.y >> 16)) + agg[3] * fac);
            *(uint2*)&AsU[2 * w + k][2 * li] = o;
        }
    }
}

// ---- gemm1 (8 waves): z1 = relu(LN256(A(16x128) @ W1^T + b1)) into LDS ----
__device__ __forceinline__ void gemm1_stage8(const ushort (*As)[136],
                                             const ushort* __restrict__ Bt,
                                             const float* __restrict__ bias,
                                             const float* __restrict__ mg,
                                             const float* __restrict__ mb,
                                             ushort (*z1s)[264],
                                             int w, int q, int ln,
                                             float (*pS)[16], float (*pQ)[16]) {
    f32x4 acc[2];
    acc[0] = (f32x4){0.f, 0.f, 0.f, 0.f};
    acc[1] = (f32x4){0.f, 0.f, 0.f, 0.f};
#pragma unroll
    for (int ks = 0; ks < 128; ks += 32) {
        bf16x8 a = *(const bf16x8*)&As[ln][ks + q * 8];
#pragma unroll
        for (int ct = 0; ct < 2; ct++) {
            bf16x8 bv = *(const bf16x8*)(Bt + (size_t)(w * 32 + ct * 16 + ln) * 128 + ks + q * 8);
            acc[ct] = __builtin_amdgcn_mfma_f32_16x16x32_bf16(a, bv, acc[ct], 0, 0, 0);
        }
    }
    float s1[4] = {0, 0, 0, 0}, s2[4] = {0, 0, 0, 0};
#pragma unroll
    for (int ct = 0; ct < 2; ct++)
#pragma unroll
        for (int r = 0; r < 4; r++) {
            float v = acc[ct][r] + bias[w * 32 + ct * 16 + ln];
            acc[ct][r] = v;
            s1[r] += v;
            s2[r] += v * v;
        }
#pragma unroll
    for (int off = 1; off < 16; off <<= 1)
#pragma unroll
        for (int r = 0; r < 4; r++) {
            s1[r] += __shfl_xor(s1[r], off, 64);
            s2[r] += __shfl_xor(s2[r], off, 64);
        }
    if (ln == 0)
#pragma unroll
        for (int r = 0; r < 4; r++) {
            pS[w][q * 4 + r] = s1[r];
            pQ[w][q * 4 + r] = s2[r];
        }
    __syncthreads();
#pragma unroll
    for (int r = 0; r < 4; r++) {
        int row = q * 4 + r;
        float S = 0.f, Q = 0.f;
#pragma unroll
        for (int ww = 0; ww < 8; ww++) {
            S += pS[ww][row];
            Q += pQ[ww][row];
        }
        float mu = S * (1.f / 256.f);
        float var = Q * (1.f / 256.f) - mu * mu;
        float rs = rsqrtf(var + 1e-5f);
#pragma unroll
        for (int ct = 0; ct < 2; ct++) {
            int col = w * 32 + ct * 16 + ln;
            float y = (acc[ct][r] - mu) * rs * mg[col] + mb[col];
            z1s[row][col] = f2bf(fmaxf(y, 0.f));
        }
    }
    __syncthreads();
}

// ---- out gemm (8 waves): h stored bf16; rowmap[row] = global node row -----
// h and rout are zero-reuse streams within a layer -> nontemporal.
template <int KD, bool RESID>
__device__ __forceinline__ void out_stage8(const ushort* __restrict__ Abase, int astr,
                                           const ushort* __restrict__ Bt,
                                           const float* __restrict__ bias,
                                           const float* __restrict__ lg,
                                           const float* __restrict__ lb,
                                           ushort* __restrict__ hbuf,
                                           ushort* __restrict__ rout,
                                           float* __restrict__ rnbuf,
                                           const int* rowmap,
                                           int w, int q, int ln,
                                           float (*pS)[16], float (*pQ)[16]) {
    f32x4 acc = (f32x4){0.f, 0.f, 0.f, 0.f};
    int col = w * 16 + ln;
#pragma unroll
    for (int ks = 0; ks < KD; ks += 32) {
        bf16x8 a = *(const bf16x8*)(Abase + ln * astr + ks + q * 8);
        bf16x8 bv = *(const bf16x8*)(Bt + (size_t)col * KD + ks + q * 8);
        acc = __builtin_amdgcn_mfma_f32_16x16x32_bf16(a, bv, acc, 0, 0, 0);
    }
    float s1[4], s2[4];
#pragma unroll
    for (int r = 0; r < 4; r++) {
        int grow = rowmap[q * 4 + r];
        float v = acc[r] + bias[col];
        if (RESID) v += bf2f(__builtin_nontemporal_load(hbuf + (size_t)grow * 128 + col));
        __builtin_nontemporal_store(f2bf(v), hbuf + (size_t)grow * 128 + col);
        acc[r] = v;
        s1[r] = v;
        s2[r] = v * v;
    }
#pragma unroll
    for (int off = 1; off < 16; off <<= 1)
#pragma unroll
        for (int r = 0; r < 4; r++) {
            s1[r] += __shfl_xor(s1[r], off, 64);
            s2[r] += __shfl_xor(s2[r], off, 64);
        }
    if (ln == 0)
#pragma unroll
        for (int r = 0; r < 4; r++) {
            pS[w][q * 4 + r] = s1[r];
            pQ[w][q * 4 + r] = s2[r];
        }
    __syncthreads();
    float yv[4];
    float t2[4];
#pragma unroll
    for (int r = 0; r < 4; r++) {
        int row = q * 4 + r;
        float S = 0.f, Q = 0.f;
#pragma unroll
        for (int ww = 0; ww < 8; ww++) {
            S += pS[ww][row];
            Q += pQ[ww][row];
        }
        float mu = S * (1.f / 128.f);
        float var = Q * (1.f / 128.f) - mu * mu;
        float rs = rsqrtf(var + 1e-5f);
        float y = (acc[r] - mu) * rs * lg[col] + lb[col];
        y = y > 0.f ? y : 0.01f * y;
        yv[r] = y;
        t2[r] = y * y;
    }
#pragma unroll
    for (int off = 1; off < 16; off <<= 1)
#pragma unroll
        for (int r = 0; r < 4; r++) t2[r] += __shfl_xor(t2[r], off, 64);
    __syncthreads();
    if (ln == 0)
#pragma unroll
        for (int r = 0; r < 4; r++) pS[w][q * 4 + r] = t2[r];
    __syncthreads();
#pragma unroll
    for (int r = 0; r < 4; r++) {
        int grow = rowmap[q * 4 + r];
        float T = 0.f;
#pragma unroll
        for (int ww = 0; ww < 8; ww++) T += pS[ww][q * 4 + r];
        if (w == 0 && ln == 0) rnbuf[grow] = sqrtf(T);
        __builtin_nontemporal_store(f2bf(yv[r]), rout + (size_t)grow * 128 + col);
    }
}

// ---------------- encoder: h = x @ encW^T + b; LN0 + lrelu -----------------
// reads x (fp32) directly; converts to bf16 in-register during LDS staging.
__global__ __launch_bounds__(BT) void enc_kernel(const float* __restrict__ x,
                                                 const ushort* __restrict__ encWt,
                                                 const float* __restrict__ encB,
                                                 const float* __restrict__ lg,
                                                 const float* __restrict__ lb,
                                                 ushort* __restrict__ h,
                                                 ushort* __restrict__ rbuf,
                                                 float* __restrict__ rn, int N) {
    __shared__ __align__(16) ushort As[16][136];
    __shared__ float pS[8][16], pQ[8][16];
    __shared__ int rowmap[16];
    uint(*AsU)[68] = (uint(*)[68])As;
    int tid = threadIdx.x, w = tid >> 6, l = tid & 63;
    int q = l >> 4, ln = l & 15;
    int row0 = blockIdx.x * 16;
    if (tid < 16) rowmap[tid] = row0 + tid;
    for (int idx = tid; idx < 16 * 64; idx += BT) {
        int row = idx >> 6, cl = idx & 63;
        f32x2 xv = __builtin_nontemporal_load(
            ((const f32x2*)x) + (size_t)(row0 + row) * 64 + cl);
        AsU[row][cl] = f2bf2(xv.x, xv.y);
    }
    __syncthreads();
    out_stage8<128, false>(&As[0][0], 136, encWt, encB, lg, lb, h, rbuf, rn,
                           rowmap, w, q, ln, pS, pQ);
}

// ---------------- fused layer: 16-row tile (perm-remapped) -----------------
__global__ __launch_bounds__(BT) void layer_kernel(const ushort* __restrict__ rin,
                                                   ushort* __restrict__ rout,
                                                   const int* __restrict__ offs,
                                                   const int* __restrict__ esrc,
                                                   const int* __restrict__ perm,
                                                   float* __restrict__ rn,
                                                   ushort* __restrict__ h,
                                                   const ushort* __restrict__ W1t,
                                                   const ushort* __restrict__ W2t,
                                                   const float* __restrict__ b1,
                                                   const float* __restrict__ mg,
                                                   const float* __restrict__ mb,
                                                   const float* __restrict__ b2,
                                                   const float* __restrict__ ng,
                                                   const float* __restrict__ nb,
                                                   const float* __restrict__ tptr,
                                                   const float* __restrict__ scptr,
                                                   int N) {
    __shared__ __align__(16) ushort As[16][136];
    __shared__ __align__(16) ushort z1s[16][264];
    __shared__ float pS[8][16], pQ[8][16];
    __shared__ int rowmap[16];
    uint(*AsU)[68] = (uint(*)[68])As;
    int tid = threadIdx.x, w = tid >> 6, l = tid & 63;
    int q = l >> 4, ln = l & 15;
    int row0 = blockIdx.x * 16;
    if (tid < 16) rowmap[tid] = perm[row0 + tid];
    __syncthreads();
    float tv2 = (*tptr) * 1.4426950408889634f;
    float sv = *scptr;
    agg_stage(rin, offs, esrc, rn, tv2, sv,
              rowmap[2 * w], rowmap[2 * w + 1], w, l, AsU);
    __syncthreads();
    gemm1_stage8(As, W1t, b1, mg, mb, z1s, w, q, ln, pS, pQ);
    out_stage8<256, true>(&z1s[0][0], 264, W2t, b2, ng, nb, h, rout, rn,
                          rowmap, w, q, ln, pS, pQ);
}

// ---------------- pool: one block per graph, 4 waves over rows -------------
__global__ __launch_bounds__(256) void pool_kernel(const ushort* __restrict__ rf,
                                                   const int* __restrict__ gstart,
                                                   float* __restrict__ out) {
    __shared__ float pb0[4][64], pb1[4][64];
    int g = blockIdx.x;
    int w = threadIdx.x >> 6, l = threadIdx.x & 63;
    int s = gstart[g], e = gstart[g + 1];
    float a0 = 0.f, a1 = 0.f;
    for (int n = s + w; n < e; n += 4) {
        uint rv = __builtin_nontemporal_load(((const uint*)rf) + (size_t)n * 64 + l);
        a0 += bf2f((ushort)(rv & 0xffff));
        a1 += bf2f((ushort)(rv >> 16));
    }
    pb0[w][l] = a0;
    pb1[w][l] = a1;
    __syncthreads();
    if (threadIdx.x < 64) {
        float t0 = pb0[0][l] + pb0[1][l] + pb0[2][l] + pb0[3][l];
        float t1 = pb1[0][l] + pb1[1][l] + pb1[2][l] + pb1[3][l];
        float inv = 1.f / fmaxf((float)(e - s), 1.f);
        out[g * 128 + 2 * l] = t0 * inv;
        out[g * 128 + 2 * l + 1] = t1 * inv;
    }
}

// ---------------------------------------------------------------------------
extern "C" void kernel_launch(void* const* d_in, const int* in_sizes, int n_in,
                              void* d_out, int out_size, void* d_ws, size_t ws_size,
                              hipStream_t stream) {
    const float* x     = (const float*)d_in[0];
    const int*   ei    = (const int*)d_in[1];
    const int*   batch = (const int*)d_in[2];
    const float* encW  = (const float*)d_in[3];
    const float* encB  = (const float*)d_in[4];
    const float* ln_g  = (const float*)d_in[5];
    const float* ln_b  = (const float*)d_in[6];
    const float* tArr  = (const float*)d_in[7];
    const float* scArr = (const float*)d_in[8];
    const float* W1    = (const float*)d_in[9];
    const float* b1    = (const float*)d_in[10];
    const float* mg    = (const float*)d_in[11];
    const float* mb    = (const float*)d_in[12];
    const float* W2    = (const float*)d_in[13];
    const float* b2    = (const float*)d_in[14];
    const float* fn_g  = (const float*)d_in[15];
    const float* fn_b  = (const float*)d_in[16];
    float* out = (float*)d_out;

    const int N = in_sizes[0] / 128;  // 10000
    const int E = in_sizes[1] / 2;    // 160000
    const int L = in_sizes[7];        // 14
    const int G = 64;

    const int* src = ei;
    const int* dst = ei + E;

    char* p = (char*)d_ws;
    auto alloc = [&](size_t bytes) -> void* {
        void* qp = (void*)p;
        p += (bytes + 255) & ~(size_t)255;
        return qp;
    };
    int*    deg    = (int*)alloc((size_t)N * 4);
    int*    offs   = (int*)alloc((size_t)(N + 1) * 4);
    int*    cursor = (int*)alloc((size_t)N * 4);
    int*    esrc   = (int*)alloc((size_t)E * 4);
    int*    gstart = (int*)alloc((size_t)(G + 1) * 4);
    int*    perm   = (int*)alloc((size_t)N * 4);
    ushort* h      = (ushort*)alloc((size_t)N * 128 * 2);
    ushort* r0     = (ushort*)alloc((size_t)N * 128 * 2);
    ushort* r1     = (ushort*)alloc((size_t)N * 128 * 2);
    float*  rn     = (float*)alloc((size_t)N * 4);
    ushort* W1t    = (ushort*)alloc((size_t)L * 32768 * 2);
    ushort* W2t    = (ushort*)alloc((size_t)L * 32768 * 2);
    ushort* encWt  = (ushort*)alloc((size_t)16384 * 2);

    (void)hipMemsetAsync(deg, 0, (size_t)N * 4, stream);

    setup_kernel<<<(E + 255) / 256, 256, 0, stream>>>(dst, deg, batch, gstart, N, E, G);
    scan_sort_kernel<<<1, 1024, 0, stream>>>(deg, offs, cursor, perm, N);
    scatter_kernel<<<(E + 255) / 256, 256, 0, stream>>>(src, dst, cursor, esrc, E);
    prep_kernel<<<dim3(8, 8, 2 * L + 1), 256, 0, stream>>>(W1, W2, encW, W1t, W2t,
                                                           encWt, L);

    const int TILES = N / 16;  // 625

    enc_kernel<<<TILES, BT, 0, stream>>>(x, encWt, encB, ln_g, ln_b, h, r0, rn, N);

    for (int i = 0; i < L; i++) {
        const ushort* rin = (i & 1) ? r1 : r0;
        ushort* rout = (i & 1) ? r0 : r1;
        const float* ng = (i < L - 1) ? (ln_g + (size_t)(i + 1) * 128) : fn_g;
        const float* nb = (i < L - 1) ? (ln_b + (size_t)(i + 1) * 128) : fn_b;
        layer_kernel<<<TILES, BT, 0, stream>>>(rin, rout, offs, esrc, perm, rn, h,
                                               W1t + ((size_t)i << 15),
                                               W2t + ((size_t)i << 15),
                                               b1 + (size_t)i * 256,
                                               mg + (size_t)i * 256,
                                               mb + (size_t)i * 256,
                                               b2 + (size_t)i * 128,
                                               ng, nb, tArr + i, scArr + i, N);
    }

    // last layer i=L-1 wrote rout = ((L-1)&1) ? r0 : r1
    const ushort* rf = ((L - 1) & 1) ? r0 : r1;
    pool_kernel<<<G, 256, 0, stream>>>(rf, gstart, out);
}

// Round 12
// 567.321 us; speedup vs baseline: 1.0883x; 1.0883x over previous
//
#include <hip/hip_runtime.h>
#include <cstdint>
#include <cstddef>

// ---------------------------------------------------------------------------
// DeeperGCN forward on MI355X. Round 32: REVERT to R30 (568.2us, session
// best). R31's wide-gather (16 j-steps) regressed to 617us -- with 16
// outstanding guarded loads the compiler's single vmcnt(0) drain covers the
// last-issued load too (window got LONGER), +32 VGPR; deg~16 nodes already
// had ~1 real window (2nd iter exec-masked cheap). Twice-confirmed lesson
// (R25, R31): the compiler's scheduling of the 8-step agg loop is locally
// optimal; source-level restructuring loses.
// This kernel = R21 lineage + setup trim (R30):
//  - xb deleted: enc reads x fp32 directly (f32x2 nontemporal), converts
//    in-register during LDS staging.
//  - scan+sort merged into one single-workgroup kernel.
//  - Layer: 512 thr / 8 waves, degree-sorted node remap, 2 equal-degree
//    nodes/wave, wave-preloaded indices + half-wave uint2 gathers, max-free
//    softmax, exp2-folded, 16-row tiles, 625 blocks, h stream bf16, nt hints.
// Status: latency-structure floor, NOT a HW roofline (HBM 5%, MFMA 1%,
// VALU 20%): 16 dependent dispatches x (launch + L2 cold-start + barrier-
// phase L3 chains). Fusion alternative measured WORSE (953us, R27) due to
// per-interval XCD coherence cost. 8 structural theories tested this arc.
// N=10000 nodes, E=160000 edges, H=128, L=14 layers, G=64 graphs.
// ---------------------------------------------------------------------------

#define BT 512  // 8 waves

typedef __attribute__((ext_vector_type(8))) short bf16x8;
typedef __attribute__((ext_vector_type(4))) float f32x4;
typedef __attribute__((ext_vector_type(2))) float f32x2;

__device__ inline float bf2f(ushort u) {
    union { uint i; float f; } v;
    v.i = (uint)u << 16;
    return v.f;
}
__device__ inline ushort f2bf(float f) {
    union { float f; uint i; } v;
    v.f = f;
    return (ushort)((v.i + 0x7fffu + ((v.i >> 16) & 1u)) >> 16);
}
__device__ inline uint f2bf2(float a, float b) {
    return (uint)f2bf(a) | ((uint)f2bf(b) << 16);
}
__device__ inline float fast_exp2(float x) {
    return __builtin_amdgcn_exp2f(x);  // v_exp_f32: D = 2^S0
}

// ---------------- setup: deg histogram + graph boundaries ------------------
__global__ void setup_kernel(const int* __restrict__ dst, int* __restrict__ deg,
                             const int* __restrict__ batch, int* __restrict__ gstart,
                             int N, int E, int G) {
    int idx = blockIdx.x * blockDim.x + threadIdx.x;
    if (idx >= E) return;
    atomicAdd(&deg[dst[idx]], 1);
    if (idx < N) {
        int bb = batch[idx];
        if (idx == 0)
            for (int g = 0; g <= bb; g++) gstart[g] = 0;
        else {
            int pb = batch[idx - 1];
            for (int g = pb + 1; g <= bb; g++) gstart[g] = idx;
        }
        if (idx == N - 1)
            for (int g = bb + 1; g <= G; g++) gstart[g] = N;
    }
}

// single-workgroup: exclusive scan of deg -> offs/cursor, then counting sort
// (perm = node ids by DESCENDING degree). Merged to save one serial launch.
__global__ __launch_bounds__(1024) void scan_sort_kernel(const int* __restrict__ deg,
                                                         int* __restrict__ offs,
                                                         int* __restrict__ cursor,
                                                         int* __restrict__ perm, int N) {
    __shared__ int part[1024];
    __shared__ int hist[256];
    __shared__ int cur[256];
    int tid = threadIdx.x;
    int CH = (N + 1023) / 1024;
    int base = tid * CH;
    int s = 0;
    for (int i = 0; i < CH; i++) {
        int idx = base + i;
        if (idx < N) s += deg[idx];
    }
    part[tid] = s;
    __syncthreads();
    for (int off = 1; off < 1024; off <<= 1) {
        int v = (tid >= off) ? part[tid - off] : 0;
        __syncthreads();
        part[tid] += v;
        __syncthreads();
    }
    int run = (tid == 0) ? 0 : part[tid - 1];
    for (int i = 0; i < CH; i++) {
        int idx = base + i;
        if (idx < N) {
            offs[idx] = run;
            cursor[idx] = run;
            run += deg[idx];
        }
    }
    if (tid == 1023) offs[N] = part[1023];

    // ---- counting sort by degree (descending) ----
    if (tid < 256) hist[tid] = 0;
    __syncthreads();
    for (int n = tid; n < N; n += 1024) {
        int key = 255 - min(deg[n], 255);
        atomicAdd(&hist[key], 1);
    }
    __syncthreads();
    if (tid == 0) {
        int r = 0;
        for (int i = 0; i < 256; i++) {
            cur[i] = r;
            r += hist[i];
        }
    }
    __syncthreads();
    for (int n = tid; n < N; n += 1024) {
        int key = 255 - min(deg[n], 255);
        int pos = atomicAdd(&cur[key], 1);
        perm[pos] = n;
    }
}

__global__ void scatter_kernel(const int* __restrict__ src, const int* __restrict__ dst,
                               int* __restrict__ cursor, int* __restrict__ esrc, int E) {
    int e = blockIdx.x * blockDim.x + threadIdx.x;
    if (e < E) {
        int d = dst[e];
        int pos = atomicAdd(&cursor[d], 1);
        esrc[pos] = src[e];
    }
}

// ---------------- weight prep: fp32 [R][C] -> bf16 [C][R], all matrices ----
__global__ __launch_bounds__(256) void prep_kernel(const float* __restrict__ W1,
                                                   const float* __restrict__ W2,
                                                   const float* __restrict__ encW,
                                                   ushort* __restrict__ W1t,
                                                   ushort* __restrict__ W2t,
                                                   ushort* __restrict__ encWt, int L) {
    __shared__ float tile[32][33];
    int z = blockIdx.z;
    const float* in;
    ushort* out;
    int R, C;
    if (z < L) {
        in = W1 + (size_t)z * 32768; out = W1t + (size_t)z * 32768; R = 128; C = 256;
    } else if (z < 2 * L) {
        int i = z - L;
        in = W2 + (size_t)i * 32768; out = W2t + (size_t)i * 32768; R = 256; C = 128;
    } else {
        in = encW; out = encWt; R = 128; C = 128;
    }
    int r0 = blockIdx.y * 32, c0 = blockIdx.x * 32;
    if (r0 >= R || c0 >= C) return;
    int tx = threadIdx.x & 31, ty = threadIdx.x >> 5;
    for (int i = ty; i < 32; i += 8) tile[i][tx] = in[(size_t)(r0 + i) * C + c0 + tx];
    __syncthreads();
    for (int i = ty; i < 32; i += 8)
        out[(size_t)(c0 + i) * R + r0 + tx] = f2bf(tile[tx][i]);
}

// ---- aggregation: 2 (perm-adjacent, equal-degree) nodes/wave --------------
__device__ __forceinline__ void agg_stage(const ushort* __restrict__ rin,
                                          const int* __restrict__ offs,
                                          const int* __restrict__ esrc,
                                          const float* __restrict__ rnbuf,
                                          float tv2, float sv,
                                          int nd0, int nd1,
                                          int w, int l, uint (*AsU)[68]) {
    const uint2* rin2 = (const uint2*)rin;
    int half = l >> 5, li = l & 31;
    int eb[2], dg[2];
    eb[0] = offs[nd0]; dg[0] = offs[nd0 + 1] - eb[0];
    eb[1] = offs[nd1]; dg[1] = offs[nd1 + 1] - eb[1];

    // prefetch (independent of gather loop): own rows + rn for both nodes
    uint2 ru0 = rin2[(size_t)nd0 * 32 + li];
    uint2 ru1 = rin2[(size_t)nd1 * 32 + li];
    float rn0 = rnbuf[nd0], rn1 = rnbuf[nd1];

    float s[2][4] = {}, W[2][4] = {};
    int mxdeg = max(dg[0], dg[1]);

#pragma unroll 1
    for (int base = 0; base < mxdeg; base += 64) {
        int rem0 = min(dg[0] - base, 64);
        int rem1 = min(dg[1] - base, 64);
        int idx0 = (rem0 > 0 && l < rem0) ? esrc[eb[0] + base + l] : 0;
        int idx1 = (rem1 > 0 && l < rem1) ? esrc[eb[1] + base + l] : 0;
        int it = (max(rem0, rem1) + 7) >> 3;
#pragma unroll 1
        for (int i = 0; i < it; i++) {
            int j0 = i * 8 + half;
            uint2 rv[2][4];
            bool vl[2][4];
#pragma unroll
            for (int c = 0; c < 4; c++) {
                int j = j0 + 2 * c;
                vl[0][c] = j < rem0;
                vl[1][c] = j < rem1;
                int sn0 = __shfl(idx0, j, 64);
                int sn1 = __shfl(idx1, j, 64);
                if (vl[0][c]) rv[0][c] = rin2[(size_t)sn0 * 32 + li];
                if (vl[1][c]) rv[1][c] = rin2[(size_t)sn1 * 32 + li];
            }
#pragma unroll
            for (int k = 0; k < 2; k++)
#pragma unroll
                for (int c = 0; c < 4; c++) {
                    if (vl[k][c]) {
                        float f0 = bf2f((ushort)(rv[k][c].x & 0xffff));
                        float f1 = bf2f((ushort)(rv[k][c].x >> 16));
                        float f2 = bf2f((ushort)(rv[k][c].y & 0xffff));
                        float f3 = bf2f((ushort)(rv[k][c].y >> 16));
                        float g0 = fmaxf(f0, 0.f) + 1e-7f;
                        float g1 = fmaxf(f1, 0.f) + 1e-7f;
                        float g2 = fmaxf(f2, 0.f) + 1e-7f;
                        float g3 = fmaxf(f3, 0.f) + 1e-7f;
                        float p0 = fast_exp2(g0 * tv2);
                        float p1 = fast_exp2(g1 * tv2);
                        float p2 = fast_exp2(g2 * tv2);
                        float p3 = fast_exp2(g3 * tv2);
                        s[k][0] += p0; W[k][0] += g0 * p0;
                        s[k][1] += p1; W[k][1] += g1 * p1;
                        s[k][2] += p2; W[k][2] += g2 * p2;
                        s[k][3] += p3; W[k][3] += g3 * p3;
                    }
                }
        }
    }

    // merge halves (associative sums), then per-node epilogue
#pragma unroll
    for (int k = 0; k < 2; k++) {
#pragma unroll
        for (int f = 0; f < 4; f++) {
            s[k][f] += __shfl_xor(s[k][f], 32, 64);
            W[k][f] += __shfl_xor(W[k][f], 32, 64);
        }
        float agg[4], nsq = 0.f;
#pragma unroll
        for (int f = 0; f < 4; f++) {
            agg[f] = W[k][f] / (s[k][f] + 1e-16f);
            nsq += agg[f] * agg[f];
        }
#pragma unroll
        for (int off = 1; off < 32; off <<= 1) nsq += __shfl_xor(nsq, off, 64);
        float rnv = (k == 0) ? rn0 : rn1;
        uint2 ru = (k == 0) ? ru0 : ru1;
        float fac = rnv * sv / fmaxf(sqrtf(nsq), 1e-12f);
        if (half == 0) {
            uint2 o;
            o.x = f2bf2(bf2f((ushort)(ru.x & 0xffff)) + agg[0] * fac,
                        bf2f((ushort)(ru.x >> 16)) + agg[1] * fac);
            o.y = f2bf2(bf2f((ushort)(ru.y & 0xffff)) + agg[2] * fac,
                        bf2f((ushort)(ru.y >> 16)) + agg[3] * fac);
            *(uint2*)&AsU[2 * w + k][2 * li] = o;
        }
    }
}

// ---- gemm1 (8 waves): z1 = relu(LN256(A(16x128) @ W1^T + b1)) into LDS ----
__device__ __forceinline__ void gemm1_stage8(const ushort (*As)[136],
                                             const ushort* __restrict__ Bt,
                                             const float* __restrict__ bias,
                                             const float* __restrict__ mg,
                                             const float* __restrict__ mb,
                                             ushort (*z1s)[264],
                                             int w, int q, int ln,
                                             float (*pS)[16], float (*pQ)[16]) {
    f32x4 acc[2];
    acc[0] = (f32x4){0.f, 0.f, 0.f, 0.f};
    acc[1] = (f32x4){0.f, 0.f, 0.f, 0.f};
#pragma unroll
    for (int ks = 0; ks < 128; ks += 32) {
        bf16x8 a = *(const bf16x8*)&As[ln][ks + q * 8];
#pragma unroll
        for (int ct = 0; ct < 2; ct++) {
            bf16x8 bv = *(const bf16x8*)(Bt + (size_t)(w * 32 + ct * 16 + ln) * 128 + ks + q * 8);
            acc[ct] = __builtin_amdgcn_mfma_f32_16x16x32_bf16(a, bv, acc[ct], 0, 0, 0);
        }
    }
    float s1[4] = {0, 0, 0, 0}, s2[4] = {0, 0, 0, 0};
#pragma unroll
    for (int ct = 0; ct < 2; ct++)
#pragma unroll
        for (int r = 0; r < 4; r++) {
            float v = acc[ct][r] + bias[w * 32 + ct * 16 + ln];
            acc[ct][r] = v;
            s1[r] += v;
            s2[r] += v * v;
        }
#pragma unroll
    for (int off = 1; off < 16; off <<= 1)
#pragma unroll
        for (int r = 0; r < 4; r++) {
            s1[r] += __shfl_xor(s1[r], off, 64);
            s2[r] += __shfl_xor(s2[r], off, 64);
        }
    if (ln == 0)
#pragma unroll
        for (int r = 0; r < 4; r++) {
            pS[w][q * 4 + r] = s1[r];
            pQ[w][q * 4 + r] = s2[r];
        }
    __syncthreads();
#pragma unroll
    for (int r = 0; r < 4; r++) {
        int row = q * 4 + r;
        float S = 0.f, Q = 0.f;
#pragma unroll
        for (int ww = 0; ww < 8; ww++) {
            S += pS[ww][row];
            Q += pQ[ww][row];
        }
        float mu = S * (1.f / 256.f);
        float var = Q * (1.f / 256.f) - mu * mu;
        float rs = rsqrtf(var + 1e-5f);
#pragma unroll
        for (int ct = 0; ct < 2; ct++) {
            int col = w * 32 + ct * 16 + ln;
            float y = (acc[ct][r] - mu) * rs * mg[col] + mb[col];
            z1s[row][col] = f2bf(fmaxf(y, 0.f));
        }
    }
    __syncthreads();
}

// ---- out gemm (8 waves): h stored bf16; rowmap[row] = global node row -----
// h and rout are zero-reuse streams within a layer -> nontemporal.
template <int KD, bool RESID>
__device__ __forceinline__ void out_stage8(const ushort* __restrict__ Abase, int astr,
                                           const ushort* __restrict__ Bt,
                                           const float* __restrict__ bias,
                                           const float* __restrict__ lg,
                                           const float* __restrict__ lb,
                                           ushort* __restrict__ hbuf,
                                           ushort* __restrict__ rout,
                                           float* __restrict__ rnbuf,
                                           const int* rowmap,
                                           int w, int q, int ln,
                                           float (*pS)[16], float (*pQ)[16]) {
    f32x4 acc = (f32x4){0.f, 0.f, 0.f, 0.f};
    int col = w * 16 + ln;
#pragma unroll
    for (int ks = 0; ks < KD; ks += 32) {
        bf16x8 a = *(const bf16x8*)(Abase + ln * astr + ks + q * 8);
        bf16x8 bv = *(const bf16x8*)(Bt + (size_t)col * KD + ks + q * 8);
        acc = __builtin_amdgcn_mfma_f32_16x16x32_bf16(a, bv, acc, 0, 0, 0);
    }
    float s1[4], s2[4];
#pragma unroll
    for (int r = 0; r < 4; r++) {
        int grow = rowmap[q * 4 + r];
        float v = acc[r] + bias[col];
        if (RESID) v += bf2f(__builtin_nontemporal_load(hbuf + (size_t)grow * 128 + col));
        __builtin_nontemporal_store(f2bf(v), hbuf + (size_t)grow * 128 + col);
        acc[r] = v;
        s1[r] = v;
        s2[r] = v * v;
    }
#pragma unroll
    for (int off = 1; off < 16; off <<= 1)
#pragma unroll
        for (int r = 0; r < 4; r++) {
            s1[r] += __shfl_xor(s1[r], off, 64);
            s2[r] += __shfl_xor(s2[r], off, 64);
        }
    if (ln == 0)
#pragma unroll
        for (int r = 0; r < 4; r++) {
            pS[w][q * 4 + r] = s1[r];
            pQ[w][q * 4 + r] = s2[r];
        }
    __syncthreads();
    float yv[4];
    float t2[4];
#pragma unroll
    for (int r = 0; r < 4; r++) {
        int row = q * 4 + r;
        float S = 0.f, Q = 0.f;
#pragma unroll
        for (int ww = 0; ww < 8; ww++) {
            S += pS[ww][row];
            Q += pQ[ww][row];
        }
        float mu = S * (1.f / 128.f);
        float var = Q * (1.f / 128.f) - mu * mu;
        float rs = rsqrtf(var + 1e-5f);
        float y = (acc[r] - mu) * rs * lg[col] + lb[col];
        y = y > 0.f ? y : 0.01f * y;
        yv[r] = y;
        t2[r] = y * y;
    }
#pragma unroll
    for (int off = 1; off < 16; off <<= 1)
#pragma unroll
        for (int r = 0; r < 4; r++) t2[r] += __shfl_xor(t2[r], off, 64);
    __syncthreads();
    if (ln == 0)
#pragma unroll
        for (int r = 0; r < 4; r++) pS[w][q * 4 + r] = t2[r];
    __syncthreads();
#pragma unroll
    for (int r = 0; r < 4; r++) {
        int grow = rowmap[q * 4 + r];
        float T = 0.f;
#pragma unroll
        for (int ww = 0; ww < 8; ww++) T += pS[ww][q * 4 + r];
        if (w == 0 && ln == 0) rnbuf[grow] = sqrtf(T);
        __builtin_nontemporal_store(f2bf(yv[r]), rout + (size_t)grow * 128 + col);
    }
}

// ---------------- encoder: h = x @ encW^T + b; LN0 + lrelu -----------------
// reads x (fp32) directly; converts to bf16 in-register during LDS staging.
__global__ __launch_bounds__(BT) void enc_kernel(const float* __restrict__ x,
                                                 const ushort* __restrict__ encWt,
                                                 const float* __restrict__ encB,
                                                 const float* __restrict__ lg,
                                                 const float* __restrict__ lb,
                                                 ushort* __restrict__ h,
                                                 ushort* __restrict__ rbuf,
                                                 float* __restrict__ rn, int N) {
    __shared__ __align__(16) ushort As[16][136];
    __shared__ float pS[8][16], pQ[8][16];
    __shared__ int rowmap[16];
    uint(*AsU)[68] = (uint(*)[68])As;
    int tid = threadIdx.x, w = tid >> 6, l = tid & 63;
    int q = l >> 4, ln = l & 15;
    int row0 = blockIdx.x * 16;
    if (tid < 16) rowmap[tid] = row0 + tid;
    for (int idx = tid; idx < 16 * 64; idx += BT) {
        int row = idx >> 6, cl = idx & 63;
        f32x2 xv = __builtin_nontemporal_load(
            ((const f32x2*)x) + (size_t)(row0 + row) * 64 + cl);
        AsU[row][cl] = f2bf2(xv.x, xv.y);
    }
    __syncthreads();
    out_stage8<128, false>(&As[0][0], 136, encWt, encB, lg, lb, h, rbuf, rn,
                           rowmap, w, q, ln, pS, pQ);
}

// ---------------- fused layer: 16-row tile (perm-remapped) -----------------
__global__ __launch_bounds__(BT) void layer_kernel(const ushort* __restrict__ rin,
                                                   ushort* __restrict__ rout,
                                                   const int* __restrict__ offs,
                                                   const int* __restrict__ esrc,
                                                   const int* __restrict__ perm,
                                                   float* __restrict__ rn,
                                                   ushort* __restrict__ h,
                                                   const ushort* __restrict__ W1t,
                                                   const ushort* __restrict__ W2t,
                                                   const float* __restrict__ b1,
                                                   const float* __restrict__ mg,
                                                   const float* __restrict__ mb,
                                                   const float* __restrict__ b2,
                                                   const float* __restrict__ ng,
                                                   const float* __restrict__ nb,
                                                   const float* __restrict__ tptr,
                                                   const float* __restrict__ scptr,
                                                   int N) {
    __shared__ __align__(16) ushort As[16][136];
    __shared__ __align__(16) ushort z1s[16][264];
    __shared__ float pS[8][16], pQ[8][16];
    __shared__ int rowmap[16];
    uint(*AsU)[68] = (uint(*)[68])As;
    int tid = threadIdx.x, w = tid >> 6, l = tid & 63;
    int q = l >> 4, ln = l & 15;
    int row0 = blockIdx.x * 16;
    if (tid < 16) rowmap[tid] = perm[row0 + tid];
    __syncthreads();
    float tv2 = (*tptr) * 1.4426950408889634f;
    float sv = *scptr;
    agg_stage(rin, offs, esrc, rn, tv2, sv,
              rowmap[2 * w], rowmap[2 * w + 1], w, l, AsU);
    __syncthreads();
    gemm1_stage8(As, W1t, b1, mg, mb, z1s, w, q, ln, pS, pQ);
    out_stage8<256, true>(&z1s[0][0], 264, W2t, b2, ng, nb, h, rout, rn,
                          rowmap, w, q, ln, pS, pQ);
}

// ---------------- pool: one block per graph, 4 waves over rows -------------
__global__ __launch_bounds__(256) void pool_kernel(const ushort* __restrict__ rf,
                                                   const int* __restrict__ gstart,
                                                   float* __restrict__ out) {
    __shared__ float pb0[4][64], pb1[4][64];
    int g = blockIdx.x;
    int w = threadIdx.x >> 6, l = threadIdx.x & 63;
    int s = gstart[g], e = gstart[g + 1];
    float a0 = 0.f, a1 = 0.f;
    for (int n = s + w; n < e; n += 4) {
        uint rv = __builtin_nontemporal_load(((const uint*)rf) + (size_t)n * 64 + l);
        a0 += bf2f((ushort)(rv & 0xffff));
        a1 += bf2f((ushort)(rv >> 16));
    }
    pb0[w][l] = a0;
    pb1[w][l] = a1;
    __syncthreads();
    if (threadIdx.x < 64) {
        float t0 = pb0[0][l] + pb0[1][l] + pb0[2][l] + pb0[3][l];
        float t1 = pb1[0][l] + pb1[1][l] + pb1[2][l] + pb1[3][l];
        float inv = 1.f / fmaxf((float)(e - s), 1.f);
        out[g * 128 + 2 * l] = t0 * inv;
        out[g * 128 + 2 * l + 1] = t1 * inv;
    }
}

// ---------------------------------------------------------------------------
extern "C" void kernel_launch(void* const* d_in, const int* in_sizes, int n_in,
                              void* d_out, int out_size, void* d_ws, size_t ws_size,
                              hipStream_t stream) {
    const float* x     = (const float*)d_in[0];
    const int*   ei    = (const int*)d_in[1];
    const int*   batch = (const int*)d_in[2];
    const float* encW  = (const float*)d_in[3];
    const float* encB  = (const float*)d_in[4];
    const float* ln_g  = (const float*)d_in[5];
    const float* ln_b  = (const float*)d_in[6];
    const float* tArr  = (const float*)d_in[7];
    const float* scArr = (const float*)d_in[8];
    const float* W1    = (const float*)d_in[9];
    const float* b1    = (const float*)d_in[10];
    const float* mg    = (const float*)d_in[11];
    const float* mb    = (const float*)d_in[12];
    const float* W2    = (const float*)d_in[13];
    const float* b2    = (const float*)d_in[14];
    const float* fn_g  = (const float*)d_in[15];
    const float* fn_b  = (const float*)d_in[16];
    float* out = (float*)d_out;

    const int N = in_sizes[0] / 128;  // 10000
    const int E = in_sizes[1] / 2;    // 160000
    const int L = in_sizes[7];        // 14
    const int G = 64;

    const int* src = ei;
    const int* dst = ei + E;

    char* p = (char*)d_ws;
    auto alloc = [&](size_t bytes) -> void* {
        void* qp = (void*)p;
        p += (bytes + 255) & ~(size_t)255;
        return qp;
    };
    int*    deg    = (int*)alloc((size_t)N * 4);
    int*    offs   = (int*)alloc((size_t)(N + 1) * 4);
    int*    cursor = (int*)alloc((size_t)N * 4);
    int*    esrc   = (int*)alloc((size_t)E * 4);
    int*    gstart = (int*)alloc((size_t)(G + 1) * 4);
    int*    perm   = (int*)alloc((size_t)N * 4);
    ushort* h      = (ushort*)alloc((size_t)N * 128 * 2);
    ushort* r0     = (ushort*)alloc((size_t)N * 128 * 2);
    ushort* r1     = (ushort*)alloc((size_t)N * 128 * 2);
    float*  rn     = (float*)alloc((size_t)N * 4);
    ushort* W1t    = (ushort*)alloc((size_t)L * 32768 * 2);
    ushort* W2t    = (ushort*)alloc((size_t)L * 32768 * 2);
    ushort* encWt  = (ushort*)alloc((size_t)16384 * 2);

    (void)hipMemsetAsync(deg, 0, (size_t)N * 4, stream);

    setup_kernel<<<(E + 255) / 256, 256, 0, stream>>>(dst, deg, batch, gstart, N, E, G);
    scan_sort_kernel<<<1, 1024, 0, stream>>>(deg, offs, cursor, perm, N);
    scatter_kernel<<<(E + 255) / 256, 256, 0, stream>>>(src, dst, cursor, esrc, E);
    prep_kernel<<<dim3(8, 8, 2 * L + 1), 256, 0, stream>>>(W1, W2, encW, W1t, W2t,
                                                           encWt, L);

    const int TILES = N / 16;  // 625

    enc_kernel<<<TILES, BT, 0, stream>>>(x, encWt, encB, ln_g, ln_b, h, r0, rn, N);

    for (int i = 0; i < L; i++) {
        const ushort* rin = (i & 1) ? r1 : r0;
        ushort* rout = (i & 1) ? r0 : r1;
        const float* ng = (i < L - 1) ? (ln_g + (size_t)(i + 1) * 128) : fn_g;
        const float* nb = (i < L - 1) ? (ln_b + (size_t)(i + 1) * 128) : fn_b;
        layer_kernel<<<TILES, BT, 0, stream>>>(rin, rout, offs, esrc, perm, rn, h,
                                               W1t + ((size_t)i << 15),
                                               W2t + ((size_t)i << 15),
                                               b1 + (size_t)i * 256,
                                               mg + (size_t)i * 256,
                                               mb + (size_t)i * 256,
                                               b2 + (size_t)i * 128,
                                               ng, nb, tArr + i, scArr + i, N);
    }

    // last layer i=L-1 wrote rout = ((L-1)&1) ? r0 : r1
    const ushort* rf = ((L - 1) & 1) ? r0 : r1;
    pool_kernel<<<G, 256, 0, stream>>>(rf, gstart, out);
}